// Round 1
// baseline (1424.971 us; speedup 1.0000x reference)
//
#include <hip/hip_runtime.h>

#define BB 4
#define CC 1024
#define TT 1024
#define HH 16
#define DD 64

// ---------------- mask expansion with dtype-layout detection ----------------
// Detect whether the bool mask arrived as int32, float32, or raw bytes by
// scanning only the first BB*TT bytes (safe under every layout).
__global__ __launch_bounds__(256) void expand_mask_kernel(const void* mraw, float* maskf) {
  __shared__ int flagA, flagB;
  if (threadIdx.x == 0) { flagA = 0; flagB = 0; }
  __syncthreads();
  const unsigned char* mb = (const unsigned char*)mraw;
  const int n = BB * TT;
  int a = 0, bfl = 0;
  for (int i = threadIdx.x; i < n; i += 256) {
    if (mb[i]) { if ((i & 3) == 0) a = 1; else bfl = 1; }
  }
  if (a)   atomicOr(&flagA, 1);
  if (bfl) atomicOr(&flagB, 1);
  __syncthreads();
  int layout;                         // 0=int32, 1=float32, 2=uint8
  if (flagA && !flagB)      layout = 0;
  else if (!flagA && flagB) layout = 1;
  else                      layout = 2;
  for (int i = threadIdx.x; i < n; i += 256) {
    float m;
    if (layout == 0)      m = (((const int*)mraw)[i]   != 0)   ? 1.f : 0.f;
    else if (layout == 1) m = (((const float*)mraw)[i] != 0.f) ? 1.f : 0.f;
    else                  m = (mb[i] != 0)                     ? 1.f : 0.f;
    maskf[i] = m;
  }
}

// ---------------- generic fp32 GEMM: O[b] = A * B[b] (+ S[b]) --------------
// A: [M,1024] row-major shared across batch; B,S,O: [*,1024] row-major with
// per-batch strides. Tile 64x64, BK=16, 256 threads, 4x4 per thread.
// LDS stride 68: conflict-free-ish writes, keeps 16B alignment for b128 reads.
__global__ __launch_bounds__(256) void gemm_f32(
    const float* __restrict__ A, const float* __restrict__ Bfull,
    const float* __restrict__ Sfull, float* __restrict__ Ofull,
    long strideB, long strideO)
{
  const float* Bm = Bfull + (long)blockIdx.z * strideB;
  float* Om = Ofull + (long)blockIdx.z * strideO;
  const float* Sm = Sfull ? (Sfull + (long)blockIdx.z * strideB) : nullptr;

  const int row0 = blockIdx.y * 64;
  const int col0 = blockIdx.x * 64;
  __shared__ float As[16][68];   // [k][m]
  __shared__ float Bs[16][68];   // [k][n]
  const int tid = threadIdx.x;
  const int tx = tid & 15, ty = tid >> 4;
  float acc[4][4] = {};

  for (int k0 = 0; k0 < CC; k0 += 16) {
#pragma unroll
    for (int it = 0; it < 4; it++) {
      int idx = tid + it * 256;
      int r = idx >> 4, c = idx & 15;
      As[c][r] = A[(long)(row0 + r) * CC + k0 + c];
      int kk = idx >> 6, nn = idx & 63;
      Bs[kk][nn] = Bm[(long)(k0 + kk) * TT + col0 + nn];
    }
    __syncthreads();
#pragma unroll
    for (int kk = 0; kk < 16; kk++) {
      float av[4], bv[4];
#pragma unroll
      for (int u = 0; u < 4; u++) av[u] = As[kk][ty * 4 + u];
#pragma unroll
      for (int v = 0; v < 4; v++) bv[v] = Bs[kk][tx * 4 + v];
#pragma unroll
      for (int u = 0; u < 4; u++)
#pragma unroll
        for (int v = 0; v < 4; v++) acc[u][v] += av[u] * bv[v];
    }
    __syncthreads();
  }
#pragma unroll
  for (int u = 0; u < 4; u++) {
    int r = row0 + ty * 4 + u;
#pragma unroll
    for (int v = 0; v < 4; v++) {
      int cidx = col0 + tx * 4 + v;
      long off = (long)r * TT + cidx;
      float val = acc[u][v];
      if (Sm) val += Sm[off];
      Om[off] = val;
    }
  }
}

// ---------------- attention logits: att[z,i,j] = <k_i,q_j>/8, key-mask -----
// z = h*BB + b. K-dim is only 64 (head dim) -> load full 64x64 K and Q slabs.
__global__ __launch_bounds__(256) void attn_logits(
    const float* __restrict__ kvq, const float* __restrict__ maskf,
    float* __restrict__ att)
{
  const int z = blockIdx.z;
  const int h = z >> 2;           // z / BB
  const int b = z & 3;            // z % BB
  const float* kb = kvq + (long)b * 3 * CC * TT + (long)(h * DD) * TT;           // k[dd][i]
  const float* qb = kvq + (long)b * 3 * CC * TT + (long)(2 * CC + h * DD) * TT;  // q[dd][j]
  const int i0 = blockIdx.y * 64, j0 = blockIdx.x * 64;

  __shared__ float Ks[64][64];
  __shared__ float Qs[64][64];
  const int tid = threadIdx.x;
#pragma unroll
  for (int it = 0; it < 16; it++) {
    int idx = tid + it * 256;
    int dd = idx >> 6, col = idx & 63;
    Ks[dd][col] = kb[(long)dd * TT + i0 + col];
    Qs[dd][col] = qb[(long)dd * TT + j0 + col];
  }
  __syncthreads();

  const int tx = tid & 15, ty = tid >> 4;
  float acc[4][4] = {};
#pragma unroll 8
  for (int dd = 0; dd < 64; dd++) {
    float av[4], bv[4];
#pragma unroll
    for (int u = 0; u < 4; u++) av[u] = Ks[dd][ty * 4 + u];
#pragma unroll
    for (int v = 0; v < 4; v++) bv[v] = Qs[dd][tx * 4 + v];
#pragma unroll
    for (int u = 0; u < 4; u++)
#pragma unroll
      for (int v = 0; v < 4; v++) acc[u][v] += av[u] * bv[v];
  }
#pragma unroll
  for (int u = 0; u < 4; u++) {
    int i = i0 + ty * 4 + u;
    float keymask = maskf[b * TT + i];
#pragma unroll
    for (int v = 0; v < 4; v++) {
      int j = j0 + tx * 4 + v;
      float l = acc[u][v] * 0.125f;
      if (keymask != 0.f) l = -1e30f;   // pre-softmax key mask (-inf analog)
      att[(long)z * TT * TT + (long)i * TT + j] = l;
    }
  }
}

// ---------------- softmax over keys (axis i, stride TT) + query-mask zero --
__global__ __launch_bounds__(256) void softmax_keys(
    float* __restrict__ att, const float* __restrict__ maskf)
{
  const int z = blockIdx.y;
  const int b = z & 3;
  const int j = blockIdx.x * 256 + threadIdx.x;
  float* col = att + (long)z * TT * TT + j;
  float m = -3.4e38f;
  for (int i = 0; i < TT; i++) m = fmaxf(m, col[(long)i * TT]);
  float s = 0.f;
  for (int i = 0; i < TT; i++) s += __expf(col[(long)i * TT] - m);
  const float inv = 1.f / s;
  const float qz = (maskf[b * TT + j] != 0.f) ? 0.f : 1.f;  // post-softmax query mask
  for (int i = 0; i < TT; i++) {
    float v = __expf(col[(long)i * TT] - m) * inv * qz;
    col[(long)i * TT] = v;
  }
}

// ---------------- o[b, h*64+dd, j] = sum_i v[dd,i] * att[z,i,j] ------------
__global__ __launch_bounds__(256) void gemm_o(
    const float* __restrict__ kvq, const float* __restrict__ att,
    float* __restrict__ obuf)
{
  const int z = blockIdx.y;
  const int h = z >> 2, b = z & 3;
  const float* vb = kvq + (long)b * 3 * CC * TT + (long)(CC + h * DD) * TT;  // v[dd][i]
  const float* am = att + (long)z * TT * TT;                                 // [i][j]
  const int j0 = blockIdx.x * 64;

  __shared__ float Vs[16][68];    // [kk][dd]
  __shared__ float As2[16][68];   // [kk][jj]
  const int tid = threadIdx.x;
  const int tx = tid & 15, ty = tid >> 4;
  float acc[4][4] = {};

  for (int i0 = 0; i0 < TT; i0 += 16) {
#pragma unroll
    for (int it = 0; it < 4; it++) {
      int idx = tid + it * 256;
      int dd = idx >> 4, kk = idx & 15;
      Vs[kk][dd] = vb[(long)dd * TT + i0 + kk];
      int kk2 = idx >> 6, jj = idx & 63;
      As2[kk2][jj] = am[(long)(i0 + kk2) * TT + j0 + jj];
    }
    __syncthreads();
#pragma unroll
    for (int kk = 0; kk < 16; kk++) {
      float av[4], bv[4];
#pragma unroll
      for (int u = 0; u < 4; u++) av[u] = Vs[kk][ty * 4 + u];
#pragma unroll
      for (int v = 0; v < 4; v++) bv[v] = As2[kk][tx * 4 + v];
#pragma unroll
      for (int u = 0; u < 4; u++)
#pragma unroll
        for (int v = 0; v < 4; v++) acc[u][v] += av[u] * bv[v];
    }
    __syncthreads();
  }
#pragma unroll
  for (int u = 0; u < 4; u++) {
    int dd = ty * 4 + u;
#pragma unroll
    for (int v = 0; v < 4; v++) {
      int j = j0 + tx * 4 + v;
      obuf[(long)b * CC * TT + (long)(h * DD + dd) * TT + j] = acc[u][v];
    }
  }
}

extern "C" void kernel_launch(void* const* d_in, const int* in_sizes, int n_in,
                              void* d_out, int out_size, void* d_ws, size_t ws_size,
                              hipStream_t stream) {
  const float* x     = (const float*)d_in[0];
  const void*  mask  = d_in[1];
  const float* w_kvq = (const float*)d_in[2];
  const float* w_out = (const float*)d_in[3];

  float* out = (float*)d_out;                     // [BB, CC, TT]
  float* att = out + (long)BB * CC * TT;          // [HH*BB, TT, TT]

  float* ws    = (float*)d_ws;
  float* maskf = ws;                              // BB*TT
  float* kvq   = ws + BB * TT;                    // BB*3*CC*TT
  float* obuf  = kvq + (long)BB * 3 * CC * TT;    // BB*CC*TT

  expand_mask_kernel<<<1, 256, 0, stream>>>(mask, maskf);
  // kvq = w_kvq · x   (M=3072, per-batch)
  gemm_f32<<<dim3(TT / 64, 3 * CC / 64, BB), 256, 0, stream>>>(
      w_kvq, x, nullptr, kvq, (long)CC * TT, (long)3 * CC * TT);
  // logits + key mask
  attn_logits<<<dim3(TT / 64, TT / 64, HH * BB), 256, 0, stream>>>(kvq, maskf, att);
  // softmax over keys + query-mask zeroing (final att output)
  softmax_keys<<<dim3(TT / 256, HH * BB), 256, 0, stream>>>(att, maskf);
  // o = v · att
  gemm_o<<<dim3(TT / 64, HH * BB), 256, 0, stream>>>(kvq, att, obuf);
  // out = x + w_out · o   (M=1024, per-batch)
  gemm_f32<<<dim3(TT / 64, CC / 64, BB), 256, 0, stream>>>(
      w_out, obuf, x, out, (long)CC * TT, (long)CC * TT);
}

// Round 2
// 1183.484 us; speedup vs baseline: 1.2040x; 1.2040x over previous
//
#include <hip/hip_runtime.h>

#define BB 4
#define CC 1024
#define TT 1024
#define HH 16
#define DD 64

// ---------------- mask expansion with dtype-layout detection ----------------
__global__ __launch_bounds__(256) void expand_mask_kernel(const void* mraw, float* maskf) {
  __shared__ int flagA, flagB;
  if (threadIdx.x == 0) { flagA = 0; flagB = 0; }
  __syncthreads();
  const unsigned char* mb = (const unsigned char*)mraw;
  const int n = BB * TT;
  int a = 0, bfl = 0;
  for (int i = threadIdx.x; i < n; i += 256) {
    if (mb[i]) { if ((i & 3) == 0) a = 1; else bfl = 1; }
  }
  if (a)   atomicOr(&flagA, 1);
  if (bfl) atomicOr(&flagB, 1);
  __syncthreads();
  int layout;                         // 0=int32, 1=float32, 2=uint8
  if (flagA && !flagB)      layout = 0;
  else if (!flagA && flagB) layout = 1;
  else                      layout = 2;
  for (int i = threadIdx.x; i < n; i += 256) {
    float m;
    if (layout == 0)      m = (((const int*)mraw)[i]   != 0)   ? 1.f : 0.f;
    else if (layout == 1) m = (((const float*)mraw)[i] != 0.f) ? 1.f : 0.f;
    else                  m = (mb[i] != 0)                     ? 1.f : 0.f;
    maskf[i] = m;
  }
}

// ---------------- generic fp32 GEMM: O[b] = A * B[b] (+ S[b]) --------------
__global__ __launch_bounds__(256) void gemm_f32(
    const float* __restrict__ A, const float* __restrict__ Bfull,
    const float* __restrict__ Sfull, float* __restrict__ Ofull,
    long strideB, long strideO)
{
  const float* Bm = Bfull + (long)blockIdx.z * strideB;
  float* Om = Ofull + (long)blockIdx.z * strideO;
  const float* Sm = Sfull ? (Sfull + (long)blockIdx.z * strideB) : nullptr;

  const int row0 = blockIdx.y * 64;
  const int col0 = blockIdx.x * 64;
  __shared__ float As[16][68];   // [k][m]
  __shared__ float Bs[16][68];   // [k][n]
  const int tid = threadIdx.x;
  const int tx = tid & 15, ty = tid >> 4;
  float acc[4][4] = {};

  for (int k0 = 0; k0 < CC; k0 += 16) {
#pragma unroll
    for (int it = 0; it < 4; it++) {
      int idx = tid + it * 256;
      int r = idx >> 4, c = idx & 15;
      As[c][r] = A[(long)(row0 + r) * CC + k0 + c];
      int kk = idx >> 6, nn = idx & 63;
      Bs[kk][nn] = Bm[(long)(k0 + kk) * TT + col0 + nn];
    }
    __syncthreads();
#pragma unroll
    for (int kk = 0; kk < 16; kk++) {
      float av[4], bv[4];
#pragma unroll
      for (int u = 0; u < 4; u++) av[u] = As[kk][ty * 4 + u];
#pragma unroll
      for (int v = 0; v < 4; v++) bv[v] = Bs[kk][tx * 4 + v];
#pragma unroll
      for (int u = 0; u < 4; u++)
#pragma unroll
        for (int v = 0; v < 4; v++) acc[u][v] += av[u] * bv[v];
    }
    __syncthreads();
  }
#pragma unroll
  for (int u = 0; u < 4; u++) {
    int r = row0 + ty * 4 + u;
#pragma unroll
    for (int v = 0; v < 4; v++) {
      int cidx = col0 + tx * 4 + v;
      long off = (long)r * TT + cidx;
      float val = acc[u][v];
      if (Sm) val += Sm[off];
      Om[off] = val;
    }
  }
}

// ---------------- attention logits + per-tile softmax partial stats --------
// att[z,i,j] = <k_i,q_j>/8 with key-mask; also emits per-(z, i-tile, j)
// partial max and sum-exp for the deferred softmax normalization.
__global__ __launch_bounds__(256) void attn_logits(
    const float* __restrict__ kvq, const float* __restrict__ maskf,
    float* __restrict__ att, float* __restrict__ pmax, float* __restrict__ psum)
{
  const int z = blockIdx.z;
  const int h = z >> 2;           // z / BB
  const int b = z & 3;            // z % BB
  const float* kb = kvq + (long)b * 3 * CC * TT + (long)(h * DD) * TT;           // k[dd][i]
  const float* qb = kvq + (long)b * 3 * CC * TT + (long)(2 * CC + h * DD) * TT;  // q[dd][j]
  const int i0 = blockIdx.y * 64, j0 = blockIdx.x * 64;

  __shared__ float Ks[64][64];    // later reused to hold the masked logits tile
  __shared__ float Qs[64][64];
  const int tid = threadIdx.x;
#pragma unroll
  for (int it = 0; it < 16; it++) {
    int idx = tid + it * 256;
    int dd = idx >> 6, col = idx & 63;
    Ks[dd][col] = kb[(long)dd * TT + i0 + col];
    Qs[dd][col] = qb[(long)dd * TT + j0 + col];
  }
  __syncthreads();

  const int tx = tid & 15, ty = tid >> 4;
  float acc[4][4] = {};
#pragma unroll 8
  for (int dd = 0; dd < 64; dd++) {
    float av[4], bv[4];
#pragma unroll
    for (int u = 0; u < 4; u++) av[u] = Ks[dd][ty * 4 + u];
#pragma unroll
    for (int v = 0; v < 4; v++) bv[v] = Qs[dd][tx * 4 + v];
#pragma unroll
    for (int u = 0; u < 4; u++)
#pragma unroll
      for (int v = 0; v < 4; v++) acc[u][v] += av[u] * bv[v];
  }
  __syncthreads();   // everyone done reading Ks/Qs; Ks now reused for logits

#pragma unroll
  for (int u = 0; u < 4; u++) {
    int il = ty * 4 + u;          // i within tile
    int i = i0 + il;
    float keymask = maskf[b * TT + i];
#pragma unroll
    for (int v = 0; v < 4; v++) {
      int jl = tx * 4 + v;
      float l = acc[u][v] * 0.125f;
      if (keymask != 0.f) l = -1e30f;   // pre-softmax key mask (-inf analog)
      att[(long)z * TT * TT + (long)i * TT + j0 + jl] = l;
      Ks[il][jl] = l;
    }
  }
  __syncthreads();

  // per-column partial stats over this 64-row i-tile (2-way bank alias: free)
  if (tid < 64) {
    float m = -3.4e38f;
#pragma unroll 8
    for (int i = 0; i < 64; i++) m = fmaxf(m, Ks[i][tid]);
    float s = 0.f;
#pragma unroll 8
    for (int i = 0; i < 64; i++) s += __expf(Ks[i][tid] - m);
    long soff = ((long)z * 16 + blockIdx.y) * TT + j0 + tid;
    pmax[soff] = m;
    psum[soff] = s;
  }
}

// ---------------- combine 16 partial stats -> (M, qz/S) per (z,j) ----------
__global__ __launch_bounds__(256) void combine_stats(
    const float* __restrict__ pmax, const float* __restrict__ psum,
    const float* __restrict__ maskf, float2* __restrict__ fstats)
{
  const int z = blockIdx.y;
  const int b = z & 3;
  const int j = blockIdx.x * 256 + threadIdx.x;
  float M = -3.4e38f;
  float pm[16];
#pragma unroll
  for (int t = 0; t < 16; t++) {
    pm[t] = pmax[((long)z * 16 + t) * TT + j];
    M = fmaxf(M, pm[t]);
  }
  float S = 0.f;
#pragma unroll
  for (int t = 0; t < 16; t++)
    S += psum[((long)z * 16 + t) * TT + j] * __expf(pm[t] - M);
  const float qz = (maskf[b * TT + j] != 0.f) ? 0.f : 1.f;  // post-softmax query mask
  fstats[(long)z * TT + j] = make_float2(M, qz / S);
}

// ------- fused: p = exp(l-M)*qz/S; att <- p; o[b,h*64+dd,j] = sum_i v*p ----
__global__ __launch_bounds__(256) void gemm_o_fused(
    const float* __restrict__ kvq, float* __restrict__ att,
    const float2* __restrict__ fstats, float* __restrict__ obuf)
{
  const int z = blockIdx.y;
  const int h = z >> 2, b = z & 3;
  const float* vb = kvq + (long)b * 3 * CC * TT + (long)(CC + h * DD) * TT;  // v[dd][i]
  float* am = att + (long)z * TT * TT;                                       // [i][j]
  const int j0 = blockIdx.x * 64;

  __shared__ float Vs[16][68];    // [kk][dd]
  __shared__ float As2[16][68];   // [kk][jj]
  const int tid = threadIdx.x;
  const int tx = tid & 15, ty = tid >> 4;
  const int jj = tid & 63;        // (tid + it*256) & 63 == tid & 63
  const float2 st = fstats[(long)z * TT + j0 + jj];   // (M, qz/S)
  float acc[4][4] = {};

  for (int i0 = 0; i0 < TT; i0 += 16) {
#pragma unroll
    for (int it = 0; it < 4; it++) {
      int idx = tid + it * 256;
      int dd = idx >> 4, kk = idx & 15;
      Vs[kk][dd] = vb[(long)dd * TT + i0 + kk];
      int kk2 = idx >> 6;
      long aoff = (long)(i0 + kk2) * TT + j0 + jj;
      float p = __expf(am[aoff] - st.x) * st.y;
      am[aoff] = p;               // final normalized+query-masked att output
      As2[kk2][jj] = p;
    }
    __syncthreads();
#pragma unroll
    for (int kk = 0; kk < 16; kk++) {
      float av[4], bv[4];
#pragma unroll
      for (int u = 0; u < 4; u++) av[u] = Vs[kk][ty * 4 + u];
#pragma unroll
      for (int v = 0; v < 4; v++) bv[v] = As2[kk][tx * 4 + v];
#pragma unroll
      for (int u = 0; u < 4; u++)
#pragma unroll
        for (int v = 0; v < 4; v++) acc[u][v] += av[u] * bv[v];
    }
    __syncthreads();
  }
#pragma unroll
  for (int u = 0; u < 4; u++) {
    int dd = ty * 4 + u;
#pragma unroll
    for (int v = 0; v < 4; v++) {
      int j = j0 + tx * 4 + v;
      obuf[(long)b * CC * TT + (long)(h * DD + dd) * TT + j] = acc[u][v];
    }
  }
}

extern "C" void kernel_launch(void* const* d_in, const int* in_sizes, int n_in,
                              void* d_out, int out_size, void* d_ws, size_t ws_size,
                              hipStream_t stream) {
  const float* x     = (const float*)d_in[0];
  const void*  mask  = d_in[1];
  const float* w_kvq = (const float*)d_in[2];
  const float* w_out = (const float*)d_in[3];

  float* out = (float*)d_out;                     // [BB, CC, TT]
  float* att = out + (long)BB * CC * TT;          // [HH*BB, TT, TT]

  float* ws     = (float*)d_ws;
  float* maskf  = ws;                             // BB*TT
  float* kvq    = ws + BB * TT;                   // BB*3*CC*TT
  float* obuf   = kvq + (long)BB * 3 * CC * TT;   // BB*CC*TT
  float* pmax   = obuf + (long)BB * CC * TT;      // 64*16*TT
  float* psum   = pmax + (long)HH * BB * 16 * TT; // 64*16*TT
  float2* fstats = (float2*)(psum + (long)HH * BB * 16 * TT); // 64*TT float2

  expand_mask_kernel<<<1, 256, 0, stream>>>(mask, maskf);
  // kvq = w_kvq · x   (M=3072, per-batch)
  gemm_f32<<<dim3(TT / 64, 3 * CC / 64, BB), 256, 0, stream>>>(
      w_kvq, x, nullptr, kvq, (long)CC * TT, (long)3 * CC * TT);
  // logits + key mask + partial softmax stats
  attn_logits<<<dim3(TT / 64, TT / 64, HH * BB), 256, 0, stream>>>(
      kvq, maskf, att, pmax, psum);
  // fold partial stats into (M, qz/S) per column
  combine_stats<<<dim3(TT / 256, HH * BB), 256, 0, stream>>>(pmax, psum, maskf, fstats);
  // normalize att in-place + o = v · att
  gemm_o_fused<<<dim3(TT / 64, HH * BB), 256, 0, stream>>>(kvq, att, fstats, obuf);
  // out = x + w_out · o   (M=1024, per-batch)
  gemm_f32<<<dim3(TT / 64, CC / 64, BB), 256, 0, stream>>>(
      w_out, obuf, x, out, (long)CC * TT, (long)CC * TT);
}

// Round 3
// 467.931 us; speedup vs baseline: 3.0453x; 2.5292x over previous
//
#include <hip/hip_runtime.h>

#define BB 4
#define CC 1024
#define TT 1024
#define HH 16
#define DD 64

typedef __bf16 v8bf __attribute__((ext_vector_type(8)));
typedef __bf16 v4bf __attribute__((ext_vector_type(4)));
typedef float  v4f  __attribute__((ext_vector_type(4)));

// ---------------- mask expansion with dtype-layout detection ----------------
__global__ __launch_bounds__(256) void expand_mask_kernel(const void* mraw, float* maskf) {
  __shared__ int flagA, flagB;
  if (threadIdx.x == 0) { flagA = 0; flagB = 0; }
  __syncthreads();
  const unsigned char* mb = (const unsigned char*)mraw;
  const int n = BB * TT;
  int a = 0, bfl = 0;
  for (int i = threadIdx.x; i < n; i += 256) {
    if (mb[i]) { if ((i & 3) == 0) a = 1; else bfl = 1; }
  }
  if (a)   atomicOr(&flagA, 1);
  if (bfl) atomicOr(&flagB, 1);
  __syncthreads();
  int layout;                         // 0=int32, 1=float32, 2=uint8
  if (flagA && !flagB)      layout = 0;
  else if (!flagA && flagB) layout = 1;
  else                      layout = 2;
  for (int i = threadIdx.x; i < n; i += 256) {
    float m;
    if (layout == 0)      m = (((const int*)mraw)[i]   != 0)   ? 1.f : 0.f;
    else if (layout == 1) m = (((const float*)mraw)[i] != 0.f) ? 1.f : 0.f;
    else                  m = (mb[i] != 0)                     ? 1.f : 0.f;
    maskf[i] = m;
  }
}

// ---------------- fp32 -> bf16 cast ----------------------------------------
__global__ __launch_bounds__(256) void cast_f32_bf16(const float* __restrict__ src,
                                                     __bf16* __restrict__ dst, int n) {
  int i = (blockIdx.x * 256 + threadIdx.x) * 8;
  if (i >= n) return;
  float4 f0 = *(const float4*)(src + i);
  float4 f1 = *(const float4*)(src + i + 4);
  v8bf o;
  o[0] = (__bf16)f0.x; o[1] = (__bf16)f0.y; o[2] = (__bf16)f0.z; o[3] = (__bf16)f0.w;
  o[4] = (__bf16)f1.x; o[5] = (__bf16)f1.y; o[6] = (__bf16)f1.z; o[7] = (__bf16)f1.w;
  *(v8bf*)(dst + i) = o;
}

// ---------------- x [b][c][t] fp32 -> xT [b][t][c] bf16 --------------------
__global__ __launch_bounds__(256) void transpose_x(const float* __restrict__ x,
                                                   __bf16* __restrict__ xT) {
  const int b = blockIdx.z;
  const int t0 = blockIdx.x * 64, c0 = blockIdx.y * 64;
  __shared__ __bf16 T[64][72];
  const int tid = threadIdx.x;
  {
    int row = tid >> 2, coff = (tid & 3) * 16;        // row: c-local, coff: t-local
    const float* src = x + ((long)b * CC + c0 + row) * TT + t0 + coff;
#pragma unroll
    for (int s = 0; s < 4; s++) {
      float4 f = *(const float4*)(src + s * 4);
      T[row][coff + s * 4 + 0] = (__bf16)f.x;
      T[row][coff + s * 4 + 1] = (__bf16)f.y;
      T[row][coff + s * 4 + 2] = (__bf16)f.z;
      T[row][coff + s * 4 + 3] = (__bf16)f.w;
    }
  }
  __syncthreads();
  {
    int trow = tid >> 2, ccoff = (tid & 3) * 16;      // trow: t-local, ccoff: c-local
    __bf16 vals[16];
#pragma unroll
    for (int i = 0; i < 16; i++) vals[i] = T[ccoff + i][trow];
    __bf16* dst = xT + ((long)b * TT + t0 + trow) * CC + c0 + ccoff;
    *(v8bf*)dst       = *(v8bf*)&vals[0];
    *(v8bf*)(dst + 8) = *(v8bf*)&vals[8];
  }
}

// ------- kvq [b][3C][T] bf16 -> kqT [b][t][2C]: [t][c]=k, [t][C+c]=q -------
__global__ __launch_bounds__(256) void transpose_kq(const __bf16* __restrict__ kvqb,
                                                    __bf16* __restrict__ kqT) {
  const int zz = blockIdx.z;
  const int b = zz >> 1, part = zz & 1;               // part 0=k (rows 0..C), 1=q (rows 2C..3C)
  const int srcbase = part == 0 ? 0 : 2 * CC;
  const int dstbase = part * CC;
  const int t0 = blockIdx.x * 64, c0 = blockIdx.y * 64;
  __shared__ __bf16 T[64][72];
  const int tid = threadIdx.x;
  {
    int row = tid >> 2, coff = (tid & 3) * 16;        // row: c-local, coff: t-local
    const __bf16* src = kvqb + ((long)b * 3 * CC + srcbase + c0 + row) * TT + t0 + coff;
    *(v8bf*)&T[row][coff]     = *(const v8bf*)src;
    *(v8bf*)&T[row][coff + 8] = *(const v8bf*)(src + 8);
  }
  __syncthreads();
  {
    int trow = tid >> 2, ccoff = (tid & 3) * 16;
    __bf16 vals[16];
#pragma unroll
    for (int i = 0; i < 16; i++) vals[i] = T[ccoff + i][trow];
    __bf16* dst = kqT + ((long)b * TT + t0 + trow) * (2 * CC) + dstbase + c0 + ccoff;
    *(v8bf*)dst       = *(v8bf*)&vals[0];
    *(v8bf*)(dst + 8) = *(v8bf*)&vals[8];
  }
}

// ------- MFMA GEMM: C[m][n] = sum_k A[m][k]*BT[n][k]  (K=1024 fixed) -------
// MODE 0: bf16 out. MODE 1: f32 out = acc + S.
template <int MODE>
__global__ __launch_bounds__(256) void gemm_bt(
    const __bf16* __restrict__ A, const __bf16* __restrict__ BTfull,
    const float* __restrict__ Sfull, void* __restrict__ Ofull,
    long strideBT, long strideOS)
{
  const __bf16* BT = BTfull + (long)blockIdx.z * strideBT;
  const int m0 = blockIdx.y * 128, n0 = blockIdx.x * 128;
  __shared__ __bf16 As[128][48];
  __shared__ __bf16 Bs[128][48];
  const int tid = threadIdx.x;
  const int lane = tid & 63, wave = tid >> 6;
  const int wm = wave >> 1, wn = wave & 1;
  const int ln = lane & 15, q = lane >> 4;

  v4f acc[4][4];
#pragma unroll
  for (int i = 0; i < 4; i++)
#pragma unroll
    for (int j = 0; j < 4; j++) acc[i][j] = (v4f)(0.f);

  const int srow = tid >> 2, skc = (tid & 3) * 8;
  for (int k0 = 0; k0 < CC; k0 += 32) {
#pragma unroll
    for (int s = 0; s < 2; s++) {
      int row = srow + s * 64;
      *(v8bf*)&As[row][skc] = *(const v8bf*)(A  + (long)(m0 + row) * CC + k0 + skc);
      *(v8bf*)&Bs[row][skc] = *(const v8bf*)(BT + (long)(n0 + row) * CC + k0 + skc);
    }
    __syncthreads();
    v8bf af[4], bf[4];
#pragma unroll
    for (int mi = 0; mi < 4; mi++) af[mi] = *(v8bf*)&As[wm * 64 + mi * 16 + ln][q * 8];
#pragma unroll
    for (int ni = 0; ni < 4; ni++) bf[ni] = *(v8bf*)&Bs[wn * 64 + ni * 16 + ln][q * 8];
#pragma unroll
    for (int mi = 0; mi < 4; mi++)
#pragma unroll
      for (int ni = 0; ni < 4; ni++)
        acc[mi][ni] = __builtin_amdgcn_mfma_f32_16x16x32_bf16(af[mi], bf[ni], acc[mi][ni], 0, 0, 0);
    __syncthreads();
  }
#pragma unroll
  for (int mi = 0; mi < 4; mi++)
#pragma unroll
    for (int ni = 0; ni < 4; ni++)
#pragma unroll
      for (int r = 0; r < 4; r++) {
        int row = m0 + wm * 64 + mi * 16 + q * 4 + r;
        int col = n0 + wn * 64 + ni * 16 + ln;
        if (MODE == 0) {
          ((__bf16*)Ofull)[(long)blockIdx.z * strideOS + (long)row * TT + col] = (__bf16)acc[mi][ni][r];
        } else {
          long off = (long)blockIdx.z * strideOS + (long)row * TT + col;
          ((float*)Ofull)[off] = acc[mi][ni][r] + Sfull[off];
        }
      }
}

// ------- stats: per (z, i-chunk 64, j) partial (max, sumexp) of logits -----
__global__ __launch_bounds__(256) void attn_stats(
    const __bf16* __restrict__ kqT, const float* __restrict__ maskf,
    float* __restrict__ pmax, float* __restrict__ psum)
{
  const int z = blockIdx.z, h = z >> 2, b = z & 3;
  const int i0 = blockIdx.y * 128, j0 = blockIdx.x * 128;
  __shared__ __bf16 Ks[128][72];
  __shared__ __bf16 Qs[128][72];
  const __bf16* kbase = kqT + (long)b * TT * (2 * CC);
  const int tid = threadIdx.x;
#pragma unroll
  for (int s = 0; s < 4; s++) {
    int c = tid + s * 256;
    int row = c >> 3, off = (c & 7) * 8;
    *(v8bf*)&Ks[row][off] = *(const v8bf*)(kbase + (long)(i0 + row) * (2 * CC) + h * DD + off);
    *(v8bf*)&Qs[row][off] = *(const v8bf*)(kbase + (long)(j0 + row) * (2 * CC) + CC + h * DD + off);
  }
  __syncthreads();
  const int lane = tid & 63, wave = tid >> 6;
  const int wi = wave >> 1, wj = wave & 1;
  const int ln = lane & 15, q = lane >> 4;

  v8bf ak[4][2], bq[4][2];
#pragma unroll
  for (int mi = 0; mi < 4; mi++)
#pragma unroll
    for (int kd = 0; kd < 2; kd++)
      ak[mi][kd] = *(v8bf*)&Ks[wi * 64 + mi * 16 + ln][kd * 32 + q * 8];
#pragma unroll
  for (int ni = 0; ni < 4; ni++)
#pragma unroll
    for (int kd = 0; kd < 2; kd++)
      bq[ni][kd] = *(v8bf*)&Qs[wj * 64 + ni * 16 + ln][kd * 32 + q * 8];

  v4f acc[4][4];
#pragma unroll
  for (int mi = 0; mi < 4; mi++)
#pragma unroll
    for (int ni = 0; ni < 4; ni++) {
      v4f a = (v4f)(0.f);
      a = __builtin_amdgcn_mfma_f32_16x16x32_bf16(ak[mi][0], bq[ni][0], a, 0, 0, 0);
      a = __builtin_amdgcn_mfma_f32_16x16x32_bf16(ak[mi][1], bq[ni][1], a, 0, 0, 0);
      acc[mi][ni] = a;
    }

  float kmv[4][4];
#pragma unroll
  for (int mi = 0; mi < 4; mi++)
#pragma unroll
    for (int r = 0; r < 4; r++)
      kmv[mi][r] = maskf[b * TT + i0 + wi * 64 + mi * 16 + q * 4 + r];

#pragma unroll
  for (int ni = 0; ni < 4; ni++) {
    float lv[16];
    float m = -3.4e38f;
#pragma unroll
    for (int mi = 0; mi < 4; mi++)
#pragma unroll
      for (int r = 0; r < 4; r++) {
        float l = (kmv[mi][r] != 0.f) ? -1e30f : acc[mi][ni][r] * 0.125f;
        lv[mi * 4 + r] = l;
        m = fmaxf(m, l);
      }
    float s = 0.f;
#pragma unroll
    for (int i = 0; i < 16; i++) s += __expf(lv[i] - m);
    // reduce across the 4 row-quads (lanes xor 16, 32)
#pragma unroll
    for (int off = 16; off <= 32; off <<= 1) {
      float om = __shfl_xor(m, off, 64);
      float os = __shfl_xor(s, off, 64);
      float M = fmaxf(m, om);
      s = s * __expf(m - M) + os * __expf(om - M);
      m = M;
    }
    if (q == 0) {
      long so = ((long)z * 16 + (i0 >> 6) + wi) * TT + j0 + wj * 64 + ni * 16 + ln;
      pmax[so] = m;
      psum[so] = s;
    }
  }
}

// ---------------- combine 16 partial stats -> (M, qz/S) per (z,j) ----------
__global__ __launch_bounds__(256) void combine_stats(
    const float* __restrict__ pmax, const float* __restrict__ psum,
    const float* __restrict__ maskf, float2* __restrict__ fstats)
{
  const int z = blockIdx.y;
  const int b = z & 3;
  const int j = blockIdx.x * 256 + threadIdx.x;
  float M = -3.4e38f;
  float pm[16];
#pragma unroll
  for (int t = 0; t < 16; t++) {
    pm[t] = pmax[((long)z * 16 + t) * TT + j];
    M = fmaxf(M, pm[t]);
  }
  float S = 0.f;
#pragma unroll
  for (int t = 0; t < 16; t++)
    S += psum[((long)z * 16 + t) * TT + j] * __expf(pm[t] - M);
  const float qz = (maskf[b * TT + j] != 0.f) ? 0.f : 1.f;
  fstats[(long)z * TT + j] = make_float2(M, qz / S);
}

// ------- recompute logits, p=exp(l-M)*qz/S -> att; o^T = p^T v^T -----------
__global__ __launch_bounds__(256) void gemm_pv(
    const __bf16* __restrict__ kqT, const __bf16* __restrict__ kvqb,
    const float2* __restrict__ fstats, const float* __restrict__ maskf,
    float* __restrict__ att, __bf16* __restrict__ oT)
{
  const int z = blockIdx.y, h = z >> 2, b = z & 3;
  const int j0 = blockIdx.x * 64;
  __shared__ __align__(16) char smem[50176];
  __bf16 (*Qs)[72] = (__bf16(*)[72])smem;                        // 64*72*2 = 9216
  float* km = (float*)(smem + 9216 + 4 * 9216);                  // 4096
  const int tid = threadIdx.x;
  const int lane = tid & 63, wave = tid >> 6;
  const int ln = lane & 15, q = lane >> 4;
  __bf16 (*Pt)[72] = (__bf16(*)[72])(smem + 9216 + wave * 9216); // per-wave 64x72

  const __bf16* kbase = kqT + (long)b * TT * (2 * CC);
  const __bf16* vbase = kvqb + (long)(b * 3 * CC + CC + h * DD) * TT;

  // stage qT slab [64 j][64 d] and the mask row
#pragma unroll
  for (int s = 0; s < 2; s++) {
    int c = tid + s * 256;
    int row = c >> 3, off = (c & 7) * 8;
    *(v8bf*)&Qs[row][off] = *(const v8bf*)(kbase + (long)(j0 + row) * (2 * CC) + CC + h * DD + off);
  }
  {
    float4 f = *(const float4*)(maskf + b * TT + tid * 4);
    *(float4*)&km[tid * 4] = f;
  }
  __syncthreads();

  v8bf bq[4][2];
#pragma unroll
  for (int ni = 0; ni < 4; ni++)
#pragma unroll
    for (int kd = 0; kd < 2; kd++)
      bq[ni][kd] = *(v8bf*)&Qs[ni * 16 + ln][kd * 32 + q * 8];
  float2 st[4];
#pragma unroll
  for (int ni = 0; ni < 4; ni++) st[ni] = fstats[(long)z * TT + j0 + ni * 16 + ln];

  v4f acc[4][4];
#pragma unroll
  for (int i = 0; i < 4; i++)
#pragma unroll
    for (int j = 0; j < 4; j++) acc[i][j] = (v4f)(0.f);

  for (int it = 0; it < 4; it++) {
    const int ibase = wave * 256 + it * 64;
    // logits (recompute, bit-identical to attn_stats) -> p -> att + Pt
#pragma unroll
    for (int mi = 0; mi < 4; mi++) {
      const __bf16* arow = kbase + (long)(ibase + mi * 16 + ln) * (2 * CC) + h * DD;
      v8bf ak0 = *(const v8bf*)(arow + q * 8);
      v8bf ak1 = *(const v8bf*)(arow + 32 + q * 8);
#pragma unroll
      for (int ni = 0; ni < 4; ni++) {
        v4f l4 = (v4f)(0.f);
        l4 = __builtin_amdgcn_mfma_f32_16x16x32_bf16(ak0, bq[ni][0], l4, 0, 0, 0);
        l4 = __builtin_amdgcn_mfma_f32_16x16x32_bf16(ak1, bq[ni][1], l4, 0, 0, 0);
        v4bf pb;
#pragma unroll
        for (int r = 0; r < 4; r++) {
          int i_loc = mi * 16 + q * 4 + r;
          int i_glob = ibase + i_loc;
          float l = (km[i_glob] != 0.f) ? -1e30f : l4[r] * 0.125f;
          float p = __expf(l - st[ni].x) * st[ni].y;
          att[((long)z << 20) + (long)i_glob * TT + j0 + ni * 16 + ln] = p;
          pb[r] = (__bf16)p;
        }
        *(v4bf*)&Pt[ni * 16 + ln][mi * 16 + q * 4] = pb;
      }
    }
    // PV: o^T[j][d] += sum_i p^T[j][i] * v^T[i][d]
    v8bf ap[4][2], bv[4][2];
#pragma unroll
    for (int ji = 0; ji < 4; ji++)
#pragma unroll
      for (int ki = 0; ki < 2; ki++)
        ap[ji][ki] = *(v8bf*)&Pt[ji * 16 + ln][ki * 32 + q * 8];
#pragma unroll
    for (int di = 0; di < 4; di++)
#pragma unroll
      for (int ki = 0; ki < 2; ki++)
        bv[di][ki] = *(const v8bf*)(vbase + (long)(di * 16 + ln) * TT + ibase + ki * 32 + q * 8);
#pragma unroll
    for (int ji = 0; ji < 4; ji++)
#pragma unroll
      for (int di = 0; di < 4; di++) {
        acc[ji][di] = __builtin_amdgcn_mfma_f32_16x16x32_bf16(ap[ji][0], bv[di][0], acc[ji][di], 0, 0, 0);
        acc[ji][di] = __builtin_amdgcn_mfma_f32_16x16x32_bf16(ap[ji][1], bv[di][1], acc[ji][di], 0, 0, 0);
      }
  }

  // cross-wave k-split reduction (serial, 4 barrier rounds)
  float (*red)[68] = (float(*)[68])(smem + 9216);
  for (int w = 0; w < 4; w++) {
    __syncthreads();
    if (wave == w) {
#pragma unroll
      for (int ji = 0; ji < 4; ji++)
#pragma unroll
        for (int di = 0; di < 4; di++)
#pragma unroll
          for (int r = 0; r < 4; r++) {
            int row = ji * 16 + q * 4 + r;
            int col = di * 16 + ln;
            if (w == 0) red[row][col] = acc[ji][di][r];
            else        red[row][col] += acc[ji][di][r];
          }
    }
  }
  __syncthreads();
  {
    int row = tid >> 2, c0 = (tid & 3) * 16;
    __bf16 ob[16];
#pragma unroll
    for (int i = 0; i < 16; i++) ob[i] = (__bf16)red[row][c0 + i];
    __bf16* dst = oT + ((long)b * TT + j0 + row) * CC + h * DD + c0;
    *(v8bf*)dst       = *(v8bf*)&ob[0];
    *(v8bf*)(dst + 8) = *(v8bf*)&ob[8];
  }
}

extern "C" void kernel_launch(void* const* d_in, const int* in_sizes, int n_in,
                              void* d_out, int out_size, void* d_ws, size_t ws_size,
                              hipStream_t stream) {
  const float* x     = (const float*)d_in[0];
  const void*  mask  = d_in[1];
  const float* w_kvq = (const float*)d_in[2];
  const float* w_out = (const float*)d_in[3];

  float* out = (float*)d_out;                     // [BB, CC, TT]
  float* att = out + (long)BB * CC * TT;          // [HH*BB, TT, TT]

  char* wsb = (char*)d_ws;
  float*   maskf = (float*)(wsb + 0);             // 16 KB
  __bf16*  wkb   = (__bf16*)(wsb + 16384);        // 6 MB
  __bf16*  wob   = (__bf16*)(wsb + 6307840);      // 2 MB
  __bf16*  xT    = (__bf16*)(wsb + 8404992);      // 8 MB   (region R)
  __bf16*  kqT   = (__bf16*)(wsb + 8404992);      // 16 MB  (region R, after xT dead)
  __bf16*  kvqb  = (__bf16*)(wsb + 25182208);     // 24 MB
  __bf16*  oT    = (__bf16*)(wsb + 50348032);     // 8 MB
  float*   pmax  = (float*)(wsb + 58736640);      // 4 MB
  float*   psum  = (float*)(wsb + 62930944);      // 4 MB
  float2*  fst   = (float2*)(wsb + 67125248);     // 0.5 MB

  expand_mask_kernel<<<1, 256, 0, stream>>>(mask, maskf);
  cast_f32_bf16<<<(3 * CC * CC) / 2048, 256, 0, stream>>>(w_kvq, wkb, 3 * CC * CC);
  cast_f32_bf16<<<(CC * CC) / 2048, 256, 0, stream>>>(w_out, wob, CC * CC);
  transpose_x<<<dim3(16, 16, BB), 256, 0, stream>>>(x, xT);
  // kvq[m][n] = sum_k w_kvq[m][k] x[k][n]
  gemm_bt<0><<<dim3(8, 24, BB), 256, 0, stream>>>(
      wkb, xT, nullptr, kvqb, (long)CC * TT, (long)3 * CC * TT);
  transpose_kq<<<dim3(16, 16, 2 * BB), 256, 0, stream>>>(kvqb, kqT);
  attn_stats<<<dim3(8, 8, HH * BB), 256, 0, stream>>>(kqT, maskf, pmax, psum);
  combine_stats<<<dim3(4, HH * BB), 256, 0, stream>>>(pmax, psum, maskf, fst);
  gemm_pv<<<dim3(16, HH * BB), 256, 0, stream>>>(kqT, kvqb, fst, maskf, att, oT);
  // out = x + w_out · o
  gemm_bt<1><<<dim3(8, 8, BB), 256, 0, stream>>>(
      wob, oT, x, out, (long)CC * TT, (long)CC * TT);
}